// Round 2
// baseline (692.165 us; speedup 1.0000x reference)
//
#include <hip/hip_runtime.h>
#include <math.h>

#define DUR 32
#define DIM 256
#define TT  528   // sum_{b} (32-b)

// ws layout (floats)
#define WS_BSUM 0       // [32]  sum of y per branch
#define WS_BSQ  32      // [32]  sum of y^2 per branch
#define WS_CY   64      // [528] sum_o y*ln_w per global t
#define WS_CW   592     // [528] sum_o ln_w
#define WS_CB   1120    // [528] sum_o ln_b
#define WS_S    1648    // [528] s = Wv @ c + 256*bv
#define WS_ZERO_FLOATS 1648

__device__ __forceinline__ float gelu_exact(float v) {
    return 0.5f * v * (1.0f + erff(v * 0.70710678118654752f));
}

// One block per (b, group of 4 o). Thread i = input channel n.
// Double-buffered weight prefetch across the 4 o's; one barrier per block;
// epilogue parallelized across the 4 waves (wave w finalizes o0+w).
__global__ __launch_bounds__(256) void conv_kernel(
    const float* __restrict__ x, const float* __restrict__ W,
    const float* __restrict__ convb, const float* __restrict__ lnw,
    const float* __restrict__ lnb, float* ws)
{
    const int n  = threadIdx.x;
    const int bb = blockIdx.x & 31;       // branch
    const int og = blockIdx.x >> 5;       // o-group (0..63)
    const int o0 = og * 4;
    const int k  = bb + 1;                // kernel width (uniform)
    const int L  = 32 - bb;               // output length (uniform)
    const int k4 = (k + 3) >> 2;

    // x column for channel n (coalesced: lane n reads x[tau*256+n])
    float xv[35];
#pragma unroll
    for (int tau = 0; tau < 32; ++tau) xv[tau] = x[tau * DIM + n];
    xv[32] = 0.f; xv[33] = 0.f; xv[34] = 0.f;   // padded taps (weights are 0 there)

    // weight double buffer: wq[buf][m] = quad m of row W[b, o, n, :]
    float4 wq[2][8];

    auto load_w = [&](int oo, int buf) {
        const float* wrow = W + (((size_t)(bb * DIM) + (size_t)(o0 + oo)) * DIM + n) * (size_t)DUR;
#pragma unroll
        for (int m = 0; m < 8; ++m) {
            if (m < k4) {   // uniform
                wq[buf][m] = *(const float4*)(wrow + 4 * m);
            } else {
                wq[buf][m] = make_float4(0.f, 0.f, 0.f, 0.f);
            }
        }
        // zero the sub-quad tail (j in [k, 4*k4))
        {
            float* wf = (float*)&wq[buf][0];
#pragma unroll
            for (int r = 0; r < 3; ++r) {
                const int j = 4 * (k4 - 1) + 1 + r;
                if (j >= k && j < 32) wf[j] = 0.f;   // uniform
            }
        }
    };

    const int wave = n >> 6;
    const int lane = n & 63;
    __shared__ float red[4][4][32];   // [o][wave][t]

    load_w(0, 0);

#pragma unroll
    for (int oo = 0; oo < 4; ++oo) {
        const int buf = oo & 1;
        if (oo < 3) load_w(oo + 1, buf ^ 1);   // prefetch next o while computing

        float acc[32];
#pragma unroll
        for (int t = 0; t < 32; ++t) acc[t] = 0.f;

        const float* wf = (const float*)&wq[buf][0];
#pragma unroll
        for (int t = 0; t < 32; ++t) {
            if (t < L) {   // uniform
#pragma unroll
                for (int m = 0; m < 8; ++m) {
                    if (m < k4) {   // uniform; zero-padded tail weights are no-ops
                        acc[t] = fmaf(xv[t + 4*m + 0], wf[4*m + 0], acc[t]);
                        acc[t] = fmaf(xv[t + 4*m + 1], wf[4*m + 1], acc[t]);
                        acc[t] = fmaf(xv[t + 4*m + 2], wf[4*m + 2], acc[t]);
                        acc[t] = fmaf(xv[t + 4*m + 3], wf[4*m + 3], acc[t]);
                    }
                }
            }
        }

        // per-wave reduce over 64 lanes; lane0 writes the wave partial
#pragma unroll
        for (int t = 0; t < 32; ++t) {
            if (t < L) {   // uniform
                float v = acc[t];
                v += __shfl_down(v, 32, 64);
                v += __shfl_down(v, 16, 64);
                v += __shfl_down(v, 8, 64);
                v += __shfl_down(v, 4, 64);
                v += __shfl_down(v, 2, 64);
                v += __shfl_down(v, 1, 64);
                if (lane == 0) red[oo][wave][t] = v;
            }
        }
    }

    __syncthreads();

    // epilogue: wave w finalizes o = o0 + w. Lanes 0..L-1 handle t.
    {
        const int o = o0 + wave;
        float g = 0.f;
        if (lane < L) {
            const float y = red[wave][0][lane] + red[wave][1][lane]
                          + red[wave][2][lane] + red[wave][3][lane]
                          + convb[bb * DIM + o];
            g = gelu_exact(y);
            const float lw = lnw[((size_t)(bb * DIM + o)) * DUR + lane];
            const float lb = lnb[((size_t)(bb * DIM + o)) * DUR + lane];
            const int tg = bb * 32 - (bb * (bb - 1)) / 2 + lane;   // concat position
            atomicAdd(ws + WS_CY + tg, g * lw);
            atomicAdd(ws + WS_CW + tg, lw);
            atomicAdd(ws + WS_CB + tg, lb);
        }
        float s1 = g, s2 = g * g;
        s1 += __shfl_down(s1, 32, 64); s2 += __shfl_down(s2, 32, 64);
        s1 += __shfl_down(s1, 16, 64); s2 += __shfl_down(s2, 16, 64);
        s1 += __shfl_down(s1, 8, 64);  s2 += __shfl_down(s2, 8, 64);
        s1 += __shfl_down(s1, 4, 64);  s2 += __shfl_down(s2, 4, 64);
        s1 += __shfl_down(s1, 2, 64);  s2 += __shfl_down(s2, 2, 64);
        s1 += __shfl_down(s1, 1, 64);  s2 += __shfl_down(s2, 1, 64);
        if (lane == 0) {
            atomicAdd(ws + WS_BSUM + bb, s1);
            atomicAdd(ws + WS_BSQ + bb, s2);
        }
    }
}

// c[t] from LN stats + colsums, then s = Wv @ c + 256*bv. 132 blocks x 4 rows.
__global__ __launch_bounds__(256) void proj1_kernel(
    float* ws, const float* __restrict__ in_proj_w,
    const float* __restrict__ in_proj_b)
{
    __shared__ float cc[TT];
    __shared__ float mu_s[32], r_s[32];
    __shared__ int map[TT];
    const int n = threadIdx.x;
    if (n < 32) {
        const int Lb = 32 - n;
        const float cnt = 256.f * (float)Lb;
        const float mu = ws[WS_BSUM + n] / cnt;
        const float var = ws[WS_BSQ + n] / cnt - mu * mu;
        mu_s[n] = mu;
        r_s[n] = rsqrtf(var + 1e-5f);
        const int off = n * 32 - (n * (n - 1)) / 2;
        for (int t = 0; t < Lb; ++t) map[off + t] = n;
    }
    __syncthreads();
    for (int t = n; t < TT; t += 256) {
        const int b = map[t];
        cc[t] = (ws[WS_CY + t] - mu_s[b] * ws[WS_CW + t]) * r_s[b] + ws[WS_CB + t];
    }
    __syncthreads();
    const int wave = n >> 6, lane = n & 63;
    const int row = blockIdx.x * 4 + wave;   // t'
    const float* Wr = in_proj_w + (size_t)(2 * TT + row) * TT;
    float a = 0.f;
    for (int t = lane; t < TT; t += 64) a = fmaf(Wr[t], cc[t], a);
    a += __shfl_down(a, 32, 64);
    a += __shfl_down(a, 16, 64);
    a += __shfl_down(a, 8, 64);
    a += __shfl_down(a, 4, 64);
    a += __shfl_down(a, 2, 64);
    a += __shfl_down(a, 1, 64);
    if (lane == 0) ws[WS_S + row] = a + 256.f * in_proj_b[2 * TT + row];
}

// S[u] = out_proj_w[u,:] . s + 256*opb[u] for u = w*128 + j (j<32); out = mean_j
__global__ __launch_bounds__(256) void proj2_kernel(
    const float* __restrict__ ws, const float* __restrict__ out_proj_w,
    const float* __restrict__ out_proj_b, float* __restrict__ out)
{
    __shared__ float sv[TT];
    __shared__ float Sacc[32];
    __shared__ float meanv;
    const int n = threadIdx.x;
    for (int t = n; t < TT; t += 256) sv[t] = ws[WS_S + t];
    __syncthreads();
    const int wave = n >> 6, lane = n & 63;
#pragma unroll
    for (int jj = 0; jj < 8; ++jj) {
        const int j = wave * 8 + jj;
        const int u = blockIdx.x * 128 + j;
        const float* Or = out_proj_w + (size_t)u * TT;
        float a = 0.f;
        for (int t = lane; t < TT; t += 64) a = fmaf(Or[t], sv[t], a);
        a += __shfl_down(a, 32, 64);
        a += __shfl_down(a, 16, 64);
        a += __shfl_down(a, 8, 64);
        a += __shfl_down(a, 4, 64);
        a += __shfl_down(a, 2, 64);
        a += __shfl_down(a, 1, 64);
        if (lane == 0) Sacc[j] = a + 256.f * out_proj_b[u];
    }
    __syncthreads();
    if (n == 0) {
        float m = 0.f;
        for (int j = 0; j < 32; ++j) m += Sacc[j];
        meanv = m * (1.0f / 32.0f);
    }
    __syncthreads();
    out[blockIdx.x * 256 + n] = meanv;
}

extern "C" void kernel_launch(void* const* d_in, const int* in_sizes, int n_in,
                              void* d_out, int out_size, void* d_ws, size_t ws_size,
                              hipStream_t stream)
{
    const float* x   = (const float*)d_in[0];
    const float* W   = (const float*)d_in[1];
    const float* cb  = (const float*)d_in[2];
    const float* lnw = (const float*)d_in[3];
    const float* lnb = (const float*)d_in[4];
    const float* ipw = (const float*)d_in[5];
    const float* ipb = (const float*)d_in[6];
    const float* opw = (const float*)d_in[7];
    const float* opb = (const float*)d_in[8];
    float* ws  = (float*)d_ws;
    float* out = (float*)d_out;

    hipMemsetAsync(ws, 0, WS_ZERO_FLOATS * sizeof(float), stream);
    conv_kernel<<<32 * 64, 256, 0, stream>>>(x, W, cb, lnw, lnb, ws);
    proj1_kernel<<<132, 256, 0, stream>>>(ws, ipw, ipb);
    proj2_kernel<<<4, 256, 0, stream>>>(ws, opw, opb, out);
}

// Round 3
// 466.673 us; speedup vs baseline: 1.4832x; 1.4832x over previous
//
#include <hip/hip_runtime.h>
#include <math.h>

#define DUR 32
#define DIM 256
#define TT  528   // sum_b (32-b)

// ws layout (floats)
#define WS_BSUM 0       // [32]
#define WS_BSQ  32      // [32]
#define WS_CY   64      // [528]
#define WS_CW   592     // [528]
#define WS_CB   1120    // [528]
#define WS_S    1648    // [528]
#define WS_S2   2176    // [128]
#define WS_ZERO_FLOATS 1648

__device__ __forceinline__ float gelu_exact(float v) {
    return 0.5f * v * (1.0f + erff(v * 0.70710678118654752f));
}

// Load one weight row into buffer BUF (compile-time!). All register indices static.
template<int BUF>
__device__ __forceinline__ void load_w(float4 (&wq)[2][8], const float* __restrict__ wrow,
                                       int k, int k4) {
#pragma unroll
    for (int m = 0; m < 8; ++m) {
        if (m < k4) {                       // uniform
            wq[BUF][m] = *(const float4*)(wrow + 4 * m);
        } else {
            wq[BUF][m] = make_float4(0.f, 0.f, 0.f, 0.f);
        }
    }
    float* wf = (float*)&wq[BUF][0];
#pragma unroll
    for (int j = 0; j < 32; ++j) { if (j >= k) wf[j] = 0.f; }  // j literal, k uniform
}

// One compute step for o-offset OO (0..3) within a batch. BUF = OO&1 (literal).
#define CONV_STEP(OO)                                                          \
  {                                                                            \
    const int idx = batch * 4 + (OO);                                          \
    if (idx + 1 < G) {  /* uniform prefetch of next o into the other buffer */ \
      load_w<((OO) + 1) & 1>(wq, W + wbb + (size_t)(o0 + idx + 1) * 8192 + nt, \
                             k, k4);                                           \
    }                                                                          \
    float acc[32];                                                             \
    _Pragma("unroll")                                                          \
    for (int t = 0; t < 32; ++t) acc[t] = 0.f;                                 \
    {                                                                          \
      const float* wf = (const float*)&wq[(OO) & 1][0];                        \
      _Pragma("unroll")                                                        \
      for (int t = 0; t < 32; ++t) {                                           \
        if (t < L) {   /* uniform */                                           \
          _Pragma("unroll")                                                    \
          for (int m = 0; m < 8; ++m) {                                        \
            if (m < k4) {  /* uniform; zero tail weights are no-ops */         \
              acc[t] = fmaf(xv[t + 4*m + 0], wf[4*m + 0], acc[t]);             \
              acc[t] = fmaf(xv[t + 4*m + 1], wf[4*m + 1], acc[t]);             \
              acc[t] = fmaf(xv[t + 4*m + 2], wf[4*m + 2], acc[t]);             \
              acc[t] = fmaf(xv[t + 4*m + 3], wf[4*m + 3], acc[t]);             \
            }                                                                  \
          }                                                                    \
        }                                                                      \
      }                                                                        \
    }                                                                          \
    _Pragma("unroll")                                                          \
    for (int t = 0; t < 32; ++t) {                                             \
      if (t < L) {   /* uniform */                                             \
        float v = acc[t];                                                      \
        v += __shfl_down(v, 32, 64);                                           \
        v += __shfl_down(v, 16, 64);                                           \
        v += __shfl_down(v, 8, 64);                                            \
        v += __shfl_down(v, 4, 64);                                            \
        v += __shfl_down(v, 2, 64);                                            \
        v += __shfl_down(v, 1, 64);                                            \
        if (lane == 0) red[batch & 1][(OO)][wave][t] = v;                      \
      }                                                                        \
    }                                                                          \
  }

// Block = (b, group of G o's), G in {16,8,4} balancing weight bytes per block.
__global__ __launch_bounds__(256) void conv_kernel(
    const float* __restrict__ x, const float* __restrict__ W,
    const float* __restrict__ convb, const float* __restrict__ lnw,
    const float* __restrict__ lnb, float* ws)
{
    const int n = threadIdx.x;
    const int id = blockIdx.x;
    int bb, og, G;
    if (id < 128)      { bb = id >> 4;               og = id & 15;        G = 16; }
    else if (id < 384) { bb = 8 + ((id - 128) >> 5); og = (id - 128) & 31; G = 8; }
    else               { bb = 16 + ((id - 384) >> 6); og = (id - 384) & 63; G = 4; }
    const int o0 = og * G;
    const int nb = G >> 2;          // batches of 4 o's
    const int k  = bb + 1;
    const int L  = 32 - bb;
    const int k4 = (k + 3) >> 2;
    const size_t wbb = (size_t)bb * 2097152;   // b * 256*256*32
    const size_t nt  = (size_t)n * DUR;

    const int wave = n >> 6;
    const int lane = n & 63;

    __shared__ float red[2][4][4][32];   // [parity][oo][writer-wave][t]
    __shared__ float epi_cy[4][32], epi_cw[4][32], epi_cb[4][32];
    __shared__ float sred[4][2];

    // x column for channel n (coalesced); taps beyond 31 hit zero weights
    float xv[35];
#pragma unroll
    for (int tau = 0; tau < 32; ++tau) xv[tau] = x[tau * DIM + n];
    xv[32] = 0.f; xv[33] = 0.f; xv[34] = 0.f;

    float4 wq[2][8];
    load_w<0>(wq, W + wbb + (size_t)o0 * 8192 + nt, k, k4);

    float cy = 0.f, cw = 0.f, cbv = 0.f, s1 = 0.f, s2 = 0.f;

    for (int batch = 0; batch < nb; ++batch) {
        CONV_STEP(0)
        CONV_STEP(1)
        CONV_STEP(2)
        CONV_STEP(3)
        __syncthreads();
        // wave w finalizes o = o0 + batch*4 + w
        const int o = o0 + batch * 4 + wave;
        float g = 0.f;
        if (lane < L) {
            const int p = batch & 1;
            const float y = red[p][wave][0][lane] + red[p][wave][1][lane]
                          + red[p][wave][2][lane] + red[p][wave][3][lane]
                          + convb[bb * DIM + o];
            g = gelu_exact(y);
            const float lw = lnw[((size_t)(bb * DIM + o)) * DUR + lane];
            const float lb = lnb[((size_t)(bb * DIM + o)) * DUR + lane];
            cy  += g * lw;
            cw  += lw;
            cbv += lb;
        }
        s1 += g;
        s2 += g * g;
    }

    // combine the 4 waves' accumulators, then one atomic set per block
    if (lane < 32) {
        epi_cy[wave][lane] = cy;
        epi_cw[wave][lane] = cw;
        epi_cb[wave][lane] = cbv;
    }
    {
        float a = s1, b2 = s2;
        a += __shfl_down(a, 32, 64);  b2 += __shfl_down(b2, 32, 64);
        a += __shfl_down(a, 16, 64);  b2 += __shfl_down(b2, 16, 64);
        a += __shfl_down(a, 8, 64);   b2 += __shfl_down(b2, 8, 64);
        a += __shfl_down(a, 4, 64);   b2 += __shfl_down(b2, 4, 64);
        a += __shfl_down(a, 2, 64);   b2 += __shfl_down(b2, 2, 64);
        a += __shfl_down(a, 1, 64);   b2 += __shfl_down(b2, 1, 64);
        if (lane == 0) { sred[wave][0] = a; sred[wave][1] = b2; }
    }
    __syncthreads();
    if (wave == 0 && lane < L) {
        const int tg = bb * 32 - (bb * (bb - 1)) / 2 + lane;
        atomicAdd(ws + WS_CY + tg,
                  epi_cy[0][lane] + epi_cy[1][lane] + epi_cy[2][lane] + epi_cy[3][lane]);
        atomicAdd(ws + WS_CW + tg,
                  epi_cw[0][lane] + epi_cw[1][lane] + epi_cw[2][lane] + epi_cw[3][lane]);
        atomicAdd(ws + WS_CB + tg,
                  epi_cb[0][lane] + epi_cb[1][lane] + epi_cb[2][lane] + epi_cb[3][lane]);
    }
    if (n == 0) {
        atomicAdd(ws + WS_BSUM + bb, sred[0][0] + sred[1][0] + sred[2][0] + sred[3][0]);
        atomicAdd(ws + WS_BSQ  + bb, sred[0][1] + sred[1][1] + sred[2][1] + sred[3][1]);
    }
}

// c[t] from LN stats + colsums, then s = Wv @ c + 256*bv. 132 blocks x 4 rows.
__global__ __launch_bounds__(256) void proj1_kernel(
    float* ws, const float* __restrict__ in_proj_w,
    const float* __restrict__ in_proj_b)
{
    __shared__ float cc[TT];
    __shared__ float mu_s[32], r_s[32];
    __shared__ int map[TT];
    const int n = threadIdx.x;
    if (n < 32) {
        const int Lb = 32 - n;
        const float cnt = 256.f * (float)Lb;
        const float mu = ws[WS_BSUM + n] / cnt;
        const float var = ws[WS_BSQ + n] / cnt - mu * mu;
        mu_s[n] = mu;
        r_s[n] = rsqrtf(var + 1e-5f);
        const int off = n * 32 - (n * (n - 1)) / 2;
        for (int t = 0; t < Lb; ++t) map[off + t] = n;
    }
    __syncthreads();
    for (int t = n; t < TT; t += 256) {
        const int b = map[t];
        cc[t] = (ws[WS_CY + t] - mu_s[b] * ws[WS_CW + t]) * r_s[b] + ws[WS_CB + t];
    }
    __syncthreads();
    const int wave = n >> 6, lane = n & 63;
    const int row = blockIdx.x * 4 + wave;
    const float* Wr = in_proj_w + (size_t)(2 * TT + row) * TT;
    float a = 0.f;
    for (int t = lane; t < TT; t += 64) a = fmaf(Wr[t], cc[t], a);
    a += __shfl_down(a, 32, 64);
    a += __shfl_down(a, 16, 64);
    a += __shfl_down(a, 8, 64);
    a += __shfl_down(a, 4, 64);
    a += __shfl_down(a, 2, 64);
    a += __shfl_down(a, 1, 64);
    if (lane == 0) ws[WS_S + row] = a + 256.f * in_proj_b[2 * TT + row];
}

// S2[i] = out_proj_w[u,:] . s + 256*opb[u], u = (i>>5)*128 + (i&31). 128 blocks.
__global__ __launch_bounds__(256) void proj2a_kernel(
    float* ws, const float* __restrict__ out_proj_w,
    const float* __restrict__ out_proj_b)
{
    const int i = blockIdx.x;
    const int u = (i >> 5) * 128 + (i & 31);
    const int n = threadIdx.x;
    const int wave = n >> 6, lane = n & 63;
    const float* Or = out_proj_w + (size_t)u * TT;
    float a = 0.f;
    for (int t = n; t < TT; t += 256) a = fmaf(Or[t], ws[WS_S + t], a);
    a += __shfl_down(a, 32, 64);
    a += __shfl_down(a, 16, 64);
    a += __shfl_down(a, 8, 64);
    a += __shfl_down(a, 4, 64);
    a += __shfl_down(a, 2, 64);
    a += __shfl_down(a, 1, 64);
    __shared__ float r4[4];
    if (lane == 0) r4[wave] = a;
    __syncthreads();
    if (n == 0) ws[WS_S2 + i] = r4[0] + r4[1] + r4[2] + r4[3] + 256.f * out_proj_b[u];
}

// out[w*256 + d] = mean_j S2[w*32 + j]. 4 blocks.
__global__ __launch_bounds__(256) void proj2b_kernel(
    const float* __restrict__ ws, float* __restrict__ out)
{
    const int n = threadIdx.x;
    __shared__ float mv;
    if (n < 64) {
        float v = (n < 32) ? ws[WS_S2 + blockIdx.x * 32 + n] : 0.f;
        v += __shfl_down(v, 16, 64);
        v += __shfl_down(v, 8, 64);
        v += __shfl_down(v, 4, 64);
        v += __shfl_down(v, 2, 64);
        v += __shfl_down(v, 1, 64);
        if (n == 0) mv = v * (1.0f / 32.0f);
    }
    __syncthreads();
    out[blockIdx.x * 256 + n] = mv;
}

extern "C" void kernel_launch(void* const* d_in, const int* in_sizes, int n_in,
                              void* d_out, int out_size, void* d_ws, size_t ws_size,
                              hipStream_t stream)
{
    const float* x   = (const float*)d_in[0];
    const float* W   = (const float*)d_in[1];
    const float* cb  = (const float*)d_in[2];
    const float* lnw = (const float*)d_in[3];
    const float* lnb = (const float*)d_in[4];
    const float* ipw = (const float*)d_in[5];
    const float* ipb = (const float*)d_in[6];
    const float* opw = (const float*)d_in[7];
    const float* opb = (const float*)d_in[8];
    float* ws  = (float*)d_ws;
    float* out = (float*)d_out;

    hipMemsetAsync(ws, 0, WS_ZERO_FLOATS * sizeof(float), stream);
    conv_kernel<<<1408, 256, 0, stream>>>(x, W, cb, lnw, lnb, ws);
    proj1_kernel<<<132, 256, 0, stream>>>(ws, ipw, ipb);
    proj2a_kernel<<<128, 256, 0, stream>>>(ws, opw, opb);
    proj2b_kernel<<<4, 256, 0, stream>>>(ws, out);
}

// Round 4
// 445.874 us; speedup vs baseline: 1.5524x; 1.0466x over previous
//
#include <hip/hip_runtime.h>
#include <math.h>

#define DUR 32
#define DIM 256
#define TT  528   // sum_b (32-b)

// ws layout (floats)
#define WS_BSUM 0       // [32]
#define WS_BSQ  32      // [32]
#define WS_CY   64      // [528]
#define WS_CW   592     // [528]
#define WS_CB   1120    // [528]
#define WS_S    1648    // [528]
#define WS_S2   2176    // [128]
#define WS_ZERO_FLOATS 1648

__device__ __forceinline__ float gelu_exact(float v) {
    return 0.5f * v * (1.0f + erff(v * 0.70710678118654752f));
}

// Block = (b, 8 consecutive o's). Coalesced prefix staging of W[b][o] into LDS,
// redistribute so thread n owns row n. K4 = ceil(k/4) compile-time.
template<int K4>
__device__ __forceinline__ void conv_body(
    const int bb, const int o0, const int tid,
    const float* __restrict__ x, const float* __restrict__ W,
    const float* __restrict__ convb, const float* __restrict__ lnw,
    const float* __restrict__ lnb, float* __restrict__ ws,
    char* __restrict__ smem, float (* __restrict__ red)[4][32],
    float (* __restrict__ epi)[4][32], float (* __restrict__ sred)[2])
{
    constexpr bool DB  = (K4 < 8);          // double-buffer unless 8 (LDS budget)
    constexpr int BUFB = 256 * 16 * K4;     // bytes per buffer
    const int k = bb + 1;                   // uniform within block
    const int L = 32 - bb;                  // uniform
    const int wave = tid >> 6;
    const int lane = tid & 63;

    // x column for channel n = tid (coalesced); taps 32..34 hit zero weights
    float xv[35];
#pragma unroll
    for (int tau = 0; tau < 32; ++tau) xv[tau] = x[tau * DIM + tid];
    xv[32] = 0.f; xv[33] = 0.f; xv[34] = 0.f;

    const float* Wb = W + (size_t)bb * (DIM * DIM * DUR) + (size_t)o0 * (DIM * DUR);

    // coalesced global load of the k4-quad prefixes into regs (prefetch buffer)
    float4 wreg[K4];
    auto issue = [&](int oo) {
#pragma unroll
        for (int r = 0; r < K4; ++r) {
            const int e = r * 256 + tid;                 // quad index in block
            wreg[r] = *(const float4*)(Wb + (size_t)oo * (DIM * DUR)
                                        + (e / K4) * 32 + (e % K4) * 4);
        }
    };
    // LDS: row n at n*16*K4; quad m stored at slot (m+n)%K4 (bank rotation)
    auto stage = [&](int p) {
#pragma unroll
        for (int r = 0; r < K4; ++r) {
            const int e = r * 256 + tid;
            const int n = e / K4, m = e % K4;
            *(float4*)(smem + p * BUFB + (n * K4 + (m + n) % K4) * 16) = wreg[r];
        }
    };

    float cy = 0.f, cw = 0.f, cbv = 0.f, s1 = 0.f, s2 = 0.f;

    auto epilogue = [&](int j) {        // finalize o = o0+j; called by one wave
        const int o = o0 + j;
        float g = 0.f;
        if (lane < L) {
            const float y = red[j & 1][0][lane] + red[j & 1][1][lane]
                          + red[j & 1][2][lane] + red[j & 1][3][lane]
                          + convb[bb * DIM + o];
            g = gelu_exact(y);
            const float lw = lnw[((size_t)(bb * DIM + o)) * DUR + lane];
            const float lb = lnb[((size_t)(bb * DIM + o)) * DUR + lane];
            cy += g * lw; cw += lw; cbv += lb;
        }
        s1 += g; s2 += g * g;
    };

    issue(0);
#pragma unroll
    for (int oo = 0; oo < 8; ++oo) {
        const int p = DB ? (oo & 1) : 0;
        if (!DB && oo > 0) __syncthreads();   // WAR barrier (single buffer only)
        stage(p);
        __syncthreads();                      // staging + red[] of oo-1 visible
        if (oo < 7) issue(oo + 1);            // global prefetch in flight

        if (oo > 0 && wave == ((oo - 1) & 3)) epilogue(oo - 1);

        float acc[32];
#pragma unroll
        for (int t = 0; t < 32; ++t) acc[t] = 0.f;

        const char* myrow = smem + p * BUFB + tid * (16 * K4);
#pragma unroll
        for (int m = 0; m < K4; ++m) {
            float4 w4 = *(const float4*)(myrow + ((m + tid) % K4) * 16);
            if (4 * m + 0 >= k) w4.x = 0.f;   // uniform k, literal j
            if (4 * m + 1 >= k) w4.y = 0.f;
            if (4 * m + 2 >= k) w4.z = 0.f;
            if (4 * m + 3 >= k) w4.w = 0.f;
#pragma unroll
            for (int t = 0; t < 32; ++t) {
                if (t < L) {   // uniform
                    acc[t] = fmaf(xv[t + 4*m + 0], w4.x, acc[t]);
                    acc[t] = fmaf(xv[t + 4*m + 1], w4.y, acc[t]);
                    acc[t] = fmaf(xv[t + 4*m + 2], w4.z, acc[t]);
                    acc[t] = fmaf(xv[t + 4*m + 3], w4.w, acc[t]);
                }
            }
        }

#pragma unroll
        for (int t = 0; t < 32; ++t) {
            if (t < L) {   // uniform
                float v = acc[t];
                v += __shfl_down(v, 32, 64);
                v += __shfl_down(v, 16, 64);
                v += __shfl_down(v, 8, 64);
                v += __shfl_down(v, 4, 64);
                v += __shfl_down(v, 2, 64);
                v += __shfl_down(v, 1, 64);
                if (lane == 0) red[oo & 1][wave][t] = v;
            }
        }
    }
    __syncthreads();
    if (wave == 3) epilogue(7);   // (7 & 3) == 3

    // cross-wave combine + one atomic set per block
    if (lane < 32) {
        epi[0][wave][lane] = cy;
        epi[1][wave][lane] = cw;
        epi[2][wave][lane] = cbv;
    }
    {
        float a = s1, b2 = s2;
        a += __shfl_down(a, 32, 64);  b2 += __shfl_down(b2, 32, 64);
        a += __shfl_down(a, 16, 64);  b2 += __shfl_down(b2, 16, 64);
        a += __shfl_down(a, 8, 64);   b2 += __shfl_down(b2, 8, 64);
        a += __shfl_down(a, 4, 64);   b2 += __shfl_down(b2, 4, 64);
        a += __shfl_down(a, 2, 64);   b2 += __shfl_down(b2, 2, 64);
        a += __shfl_down(a, 1, 64);   b2 += __shfl_down(b2, 1, 64);
        if (lane == 0) { sred[wave][0] = a; sred[wave][1] = b2; }
    }
    __syncthreads();
    if (wave == 0 && lane < L) {
        const int tg = bb * 32 - (bb * (bb - 1)) / 2 + lane;
        atomicAdd(ws + WS_CY + tg, epi[0][0][lane] + epi[0][1][lane] + epi[0][2][lane] + epi[0][3][lane]);
        atomicAdd(ws + WS_CW + tg, epi[1][0][lane] + epi[1][1][lane] + epi[1][2][lane] + epi[1][3][lane]);
        atomicAdd(ws + WS_CB + tg, epi[2][0][lane] + epi[2][1][lane] + epi[2][2][lane] + epi[2][3][lane]);
    }
    if (tid == 0) {
        atomicAdd(ws + WS_BSUM + bb, sred[0][0] + sred[1][0] + sred[2][0] + sred[3][0]);
        atomicAdd(ws + WS_BSQ  + bb, sred[0][1] + sred[1][1] + sred[2][1] + sred[3][1]);
    }
}

__global__ __launch_bounds__(256) void conv_kernel(
    const float* __restrict__ x, const float* __restrict__ W,
    const float* __restrict__ convb, const float* __restrict__ lnw,
    const float* __restrict__ lnb, float* ws)
{
    __shared__ char  smem[57344];        // max: K4=7 double-buffered
    __shared__ float red[2][4][32];
    __shared__ float epi[3][4][32];
    __shared__ float sred[4][2];

    const int bid = blockIdx.x;
    const int bb  = 31 - (bid & 31);     // mix classes across CUs, heavy first
    const int o0  = (bid >> 5) * 8;
    const int tid = threadIdx.x;

    switch (bb >> 2) {
        case 0: conv_body<1>(bb, o0, tid, x, W, convb, lnw, lnb, ws, smem, red, epi, sred); break;
        case 1: conv_body<2>(bb, o0, tid, x, W, convb, lnw, lnb, ws, smem, red, epi, sred); break;
        case 2: conv_body<3>(bb, o0, tid, x, W, convb, lnw, lnb, ws, smem, red, epi, sred); break;
        case 3: conv_body<4>(bb, o0, tid, x, W, convb, lnw, lnb, ws, smem, red, epi, sred); break;
        case 4: conv_body<5>(bb, o0, tid, x, W, convb, lnw, lnb, ws, smem, red, epi, sred); break;
        case 5: conv_body<6>(bb, o0, tid, x, W, convb, lnw, lnb, ws, smem, red, epi, sred); break;
        case 6: conv_body<7>(bb, o0, tid, x, W, convb, lnw, lnb, ws, smem, red, epi, sred); break;
        default: conv_body<8>(bb, o0, tid, x, W, convb, lnw, lnb, ws, smem, red, epi, sred); break;
    }
}

// c[t] from LN stats + colsums, then s = Wv @ c + 256*bv. 132 blocks x 4 rows.
__global__ __launch_bounds__(256) void proj1_kernel(
    float* ws, const float* __restrict__ in_proj_w,
    const float* __restrict__ in_proj_b)
{
    __shared__ float cc[TT];
    __shared__ float mu_s[32], r_s[32];
    __shared__ int map[TT];
    const int n = threadIdx.x;
    if (n < 32) {
        const int Lb = 32 - n;
        const float cnt = 256.f * (float)Lb;
        const float mu = ws[WS_BSUM + n] / cnt;
        const float var = ws[WS_BSQ + n] / cnt - mu * mu;
        mu_s[n] = mu;
        r_s[n] = rsqrtf(var + 1e-5f);
        const int off = n * 32 - (n * (n - 1)) / 2;
        for (int t = 0; t < Lb; ++t) map[off + t] = n;
    }
    __syncthreads();
    for (int t = n; t < TT; t += 256) {
        const int b = map[t];
        cc[t] = (ws[WS_CY + t] - mu_s[b] * ws[WS_CW + t]) * r_s[b] + ws[WS_CB + t];
    }
    __syncthreads();
    const int wave = n >> 6, lane = n & 63;
    const int row = blockIdx.x * 4 + wave;
    const float* Wr = in_proj_w + (size_t)(2 * TT + row) * TT;
    float a = 0.f;
    for (int t = lane; t < TT; t += 64) a = fmaf(Wr[t], cc[t], a);
    a += __shfl_down(a, 32, 64);
    a += __shfl_down(a, 16, 64);
    a += __shfl_down(a, 8, 64);
    a += __shfl_down(a, 4, 64);
    a += __shfl_down(a, 2, 64);
    a += __shfl_down(a, 1, 64);
    if (lane == 0) ws[WS_S + row] = a + 256.f * in_proj_b[2 * TT + row];
}

// S2[i] = out_proj_w[u,:] . s + 256*opb[u], u = (i>>5)*128 + (i&31). 128 blocks.
__global__ __launch_bounds__(256) void proj2a_kernel(
    float* ws, const float* __restrict__ out_proj_w,
    const float* __restrict__ out_proj_b)
{
    const int i = blockIdx.x;
    const int u = (i >> 5) * 128 + (i & 31);
    const int n = threadIdx.x;
    const int wave = n >> 6, lane = n & 63;
    const float* Or = out_proj_w + (size_t)u * TT;
    float a = 0.f;
    for (int t = n; t < TT; t += 256) a = fmaf(Or[t], ws[WS_S + t], a);
    a += __shfl_down(a, 32, 64);
    a += __shfl_down(a, 16, 64);
    a += __shfl_down(a, 8, 64);
    a += __shfl_down(a, 4, 64);
    a += __shfl_down(a, 2, 64);
    a += __shfl_down(a, 1, 64);
    __shared__ float r4[4];
    if (lane == 0) r4[wave] = a;
    __syncthreads();
    if (n == 0) ws[WS_S2 + i] = r4[0] + r4[1] + r4[2] + r4[3] + 256.f * out_proj_b[u];
}

// out[w*256 + d] = mean_j S2[w*32 + j]. 4 blocks.
__global__ __launch_bounds__(256) void proj2b_kernel(
    const float* __restrict__ ws, float* __restrict__ out)
{
    const int n = threadIdx.x;
    __shared__ float mv;
    if (n < 64) {
        float v = (n < 32) ? ws[WS_S2 + blockIdx.x * 32 + n] : 0.f;
        v += __shfl_down(v, 16, 64);
        v += __shfl_down(v, 8, 64);
        v += __shfl_down(v, 4, 64);
        v += __shfl_down(v, 2, 64);
        v += __shfl_down(v, 1, 64);
        if (n == 0) mv = v * (1.0f / 32.0f);
    }
    __syncthreads();
    out[blockIdx.x * 256 + n] = mv;
}

extern "C" void kernel_launch(void* const* d_in, const int* in_sizes, int n_in,
                              void* d_out, int out_size, void* d_ws, size_t ws_size,
                              hipStream_t stream)
{
    const float* x   = (const float*)d_in[0];
    const float* W   = (const float*)d_in[1];
    const float* cb  = (const float*)d_in[2];
    const float* lnw = (const float*)d_in[3];
    const float* lnb = (const float*)d_in[4];
    const float* ipw = (const float*)d_in[5];
    const float* ipb = (const float*)d_in[6];
    const float* opw = (const float*)d_in[7];
    const float* opb = (const float*)d_in[8];
    float* ws  = (float*)d_ws;
    float* out = (float*)d_out;

    hipMemsetAsync(ws, 0, WS_ZERO_FLOATS * sizeof(float), stream);
    conv_kernel<<<1024, 256, 0, stream>>>(x, W, cb, lnw, lnb, ws);
    proj1_kernel<<<132, 256, 0, stream>>>(ws, ipw, ipb);
    proj2a_kernel<<<128, 256, 0, stream>>>(ws, opw, opb);
    proj2b_kernel<<<4, 256, 0, stream>>>(ws, out);
}